// Round 16
// baseline (277.357 us; speedup 1.0000x reference)
//
#include <hip/hip_runtime.h>
#include <math.h>

#define M_GRID 128
#define J_FEAT 80
#define NNET   160   // NBASE*J_FEAT
#define HDIM   256

typedef __attribute__((ext_vector_type(8))) short v8s;   // 8 bf16
typedef __attribute__((ext_vector_type(4))) float f4;    // MFMA accum / float4

__device__ __forceinline__ unsigned short f2bf(float f) {
    unsigned u = __float_as_uint(f);
    u += 0x7fffu + ((u >> 16) & 1u);   // round-to-nearest-even
    return (unsigned short)(u >> 16);
}

__device__ __forceinline__ float selu_f(float x) {
    const float SC = 1.0507009873554805f;
    const float AL = 1.6732632423543772f;
    return x > 0.f ? SC * x : SC * AL * (__expf(x) - 1.f);
}

#define RAW_BAR() do { __builtin_amdgcn_sched_barrier(0);                  \
                       __builtin_amdgcn_s_barrier(); } while (0)

// One workgroup per network n. 1024 threads = 16 waves, role-split:
//   waves 0-7  (cons): r15's compute path -- 16 rows/wave, act in LDS,
//     acc[16]; ZERO VMEM inside the K-loop (clean vmcnt for producers).
//   waves 8-15 (prod): stream W via ordinary VMEM into a SINGLE rr[16]
//     register set (depth-1: stage q+1 loads issued one body ahead; a body
//     is ~1.5-3 us >> 600 ns L3 latency), convert into the double-buffered
//     XOR-swizzled bf16 tile.  Single set keeps loop-scope liveness to
//     acc 64 + rr 16 ~= 80 regs -> fits the 128/wave budget at 4 waves/SIMD
//     (r15's rr[2][16]+acc was 96 baseline and spilled at peaks).
// WHY 16 waves: per-CU read BW scales with resident waves (~10-12 GB/s at
// 8 waves across r10/r15 regardless of DMA vs VMEM; fillBuffer hits 27
// GB/s/CU at 32 waves).  Doubling waves/CU should roughly double the
// per-CU streaming rate that bounds this kernel.
// Body q: cons MFMA stage q from tile[q&1] (+ epilogue at q%8==7);
//         prod convert stage q+1 -> tile[(q+1)&1], issue stage q+2.
// Barrier count is identical across roles (BAR_a, BAR_0, 24 body BARs).
// LDS 110 KB: tiles 2x16K @0, act @32K (8 cons waves x 8K), params @96K.
__attribute__((amdgpu_flat_work_group_size(1024, 1024)))
__global__ void basis_kernel(const float* __restrict__ t,
                             const float* __restrict__ W_in,
                             const float* __restrict__ b_in,
                             const float* __restrict__ W_h,
                             const float* __restrict__ b_h,
                             const float* __restrict__ W_out,
                             const float* __restrict__ b_out,
                             const float* __restrict__ ln_a,
                             const float* __restrict__ ln_b,
                             float* __restrict__ basesT)   // [M][NNET]
{
    extern __shared__ __align__(16) unsigned char lds[];   // 112640 B
    const int n    = blockIdx.x;
    const int tid  = threadIdx.x;
    const int l    = tid & 63;
    const int wv   = tid >> 6;          // wave 0..15
    const bool cons = (wv < 8);
    const int c    = wv & 7;            // consumer wave id
    const int lr   = l & 15;
    const int g    = l >> 4;            // k-group
    const int ptid = tid & 511;         // producer-local tid
    const int jcol = ptid & 255;        // staging column
    const int o8   = ptid >> 8;         // staging k-half (0/1)

    unsigned char* const actw = lds + 32768 + (size_t)c * 8192;
    float* const P = (float*)(lds + 98304);
    // P groups (256 floats): 0=wo, 1-3=ln_a L1..3, 4-6=ln_b L1..3,
    // 7-9=b_h L0..2, 10=wi, 11=bi, 12=ln_a L0, 13=ln_b L0.

    // -------- producer staging helpers (r15-proven layout/swizzle) --------
    float rr[16];
    auto issue = [&](int q) {   // q = global stage 0..23
        const float* Wq = W_h + ((size_t)((q >> 3) * NNET + n) << 16)
                        + (size_t)((q & 7) * 32 + o8 * 16) * HDIM + jcol;
        #pragma unroll
        for (int i = 0; i < 16; ++i) rr[i] = Wq[(size_t)i * HDIM];
    };
    auto convert_store = [&](int bufp) {
        #pragma unroll
        for (int o = 0; o < 2; ++o) {
            v8s pk;
            #pragma unroll
            for (int i = 0; i < 8; ++i) pk[i] = (short)f2bf(rr[o * 8 + i]);
            int byte = (bufp << 14) + (o8 << 13) + jcol * 32 + (o << 4);
            byte ^= ((jcol >> 2) & 7) << 4;
            *(v8s*)(lds + byte) = pk;
        }
    };

    // -------- phase A: cons stage params, prod issue stage 0 --------
    if (cons) {
        const size_t nb = (size_t)n * HDIM;
        #pragma unroll
        for (int i = 0; i < 7; ++i) {
            const int idx = tid + (i << 9), grp = idx >> 8, off = idx & 255;
            float v;
            if (grp == 0)       v = W_out[nb + off];
            else if (grp < 4)   v = ln_a[((size_t)grp * NNET + n) * HDIM + off];
            else if (grp < 7)   v = ln_b[((size_t)(grp - 3) * NNET + n) * HDIM + off];
            else if (grp < 10)  v = b_h[((size_t)(grp - 7) * NNET + n) * HDIM + off];
            else if (grp == 10) v = W_in[nb + off];
            else if (grp == 11) v = b_in[nb + off];
            else if (grp == 12) v = ln_a[nb + off];
            else                v = ln_b[nb + off];
            P[idx] = v;
        }
        asm volatile("s_waitcnt lgkmcnt(0)" ::: "memory");
    } else {
        issue(0);
    }
    RAW_BAR();   // BAR_a: params visible; prod loads stay in flight

    // -------- phase B: cons input layer, prod convert(0)+issue(1) --------
    if (cons) {
        const float tval = t[c * 16 + lr];
        const float* wi = P + 2560; const float* bi = P + 2816;
        const float* la = P + 3072; const float* lb = P + 3328;
        float s_ = 0.f, q_ = 0.f;
        #pragma unroll
        for (int kt = 0; kt < 8; ++kt) {
            const int h0 = kt * 32 + g * 8;
            const f4 w0 = *(const f4*)(wi + h0), w1 = *(const f4*)(wi + h0 + 4);
            const f4 b0 = *(const f4*)(bi + h0), b1 = *(const f4*)(bi + h0 + 4);
            #pragma unroll
            for (int i = 0; i < 4; ++i) {
                float v0 = __builtin_fmaf(tval, w0[i], b0[i]);
                float v1 = __builtin_fmaf(tval, w1[i], b1[i]);
                s_ += v0 + v1; q_ += v0 * v0 + v1 * v1;
            }
        }
        s_ += __shfl_xor(s_, 16); q_ += __shfl_xor(q_, 16);
        s_ += __shfl_xor(s_, 32); q_ += __shfl_xor(q_, 32);
        const float mean = s_ * (1.f / 256.f);
        const float var  = (q_ - s_ * s_ * (1.f / 256.f)) * (1.f / 255.f); // unbiased
        const float inv  = 1.f / (sqrtf(var) + 1e-6f);                     // eps on std
        asm volatile("" ::: "memory");   // forbid CSE of pass-1 reads
        #pragma unroll
        for (int kt = 0; kt < 8; ++kt) {
            const int h0 = kt * 32 + g * 8;
            const f4 w0 = *(const f4*)(wi + h0), w1 = *(const f4*)(wi + h0 + 4);
            const f4 b0 = *(const f4*)(bi + h0), b1 = *(const f4*)(bi + h0 + 4);
            const f4 a0 = *(const f4*)(la + h0), a1 = *(const f4*)(la + h0 + 4);
            const f4 e0 = *(const f4*)(lb + h0), e1 = *(const f4*)(lb + h0 + 4);
            v8s a;
            #pragma unroll
            for (int i = 0; i < 4; ++i) {
                float v0 = __builtin_fmaf(tval, w0[i], b0[i]);
                float v1 = __builtin_fmaf(tval, w1[i], b1[i]);
                a[i]     = (short)f2bf(selu_f(v0 + (v0 - mean) * inv * a0[i] + e0[i]));
                a[i + 4] = (short)f2bf(selu_f(v1 + (v1 - mean) * inv * a1[i] + e1[i]));
            }
            *(v8s*)(actw + ((lr * 512 + h0 * 2) ^ (lr << 5))) = a;
        }
        asm volatile("s_waitcnt lgkmcnt(0)" ::: "memory");  // act wave-private
    } else {
        convert_store(0);   // waits rr (stage 0) via compiler-counted vmcnt
        asm volatile("s_waitcnt lgkmcnt(0)" ::: "memory");
        issue(1);
    }
    RAW_BAR();   // BAR_0: tile0 ready, act ready

    f4 acc[16];

    #pragma unroll 1
    for (int q = 0; q < 24; ++q) {
        if (cons) {
            const int s = q & 7, L = q >> 3;
            if (s == 0) {
                const f4 zero = {0.f, 0.f, 0.f, 0.f};
                #pragma unroll
                for (int ct = 0; ct < 16; ++ct) acc[ct] = zero;
            }
            const v8s af = *(const v8s*)(actw + ((lr * 512 + (s * 32 + g * 8) * 2) ^ (lr << 5)));
            #pragma unroll
            for (int cc = 0; cc < 4; ++cc) {
                #pragma unroll
                for (int c4 = 0; c4 < 4; ++c4) {
                    const int ct = cc * 4 + c4;
                    const int jb = ct * 16 + lr;
                    int byte = ((q & 1) << 14) + ((g >> 1) << 13) + jb * 32 + ((g & 1) << 4);
                    byte ^= ((jb >> 2) & 7) << 4;
                    const v8s bf = *(const v8s*)(lds + byte);
                    acc[ct] = __builtin_amdgcn_mfma_f32_16x16x32_bf16(af, bf, acc[ct], 0, 0, 0);
                }
                __builtin_amdgcn_sched_barrier(0);   // cap transient ds-read pressure
            }
            if (s == 7) {
                // ---------------- epilogue for layer L ----------------
                const float* bh = P + (7 + L) * 256;
                const float* la = P + (1 + L) * 256;
                const float* lb = P + (4 + L) * 256;
                float sums[4] = {0,0,0,0}, sqs[4] = {0,0,0,0};
                #pragma unroll
                for (int ct = 0; ct < 16; ++ct) {
                    const float bias = bh[ct * 16 + lr];
                    #pragma unroll
                    for (int r = 0; r < 4; ++r) {
                        float v = acc[ct][r] + bias;
                        acc[ct][r] = v;
                        sums[r] += v; sqs[r] += v * v;
                    }
                }
                #pragma unroll
                for (int r = 0; r < 4; ++r)
                    #pragma unroll
                    for (int m = 1; m <= 8; m <<= 1) {
                        sums[r] += __shfl_xor(sums[r], m);
                        sqs[r]  += __shfl_xor(sqs[r],  m);
                    }
                float mean[4], inv[4];
                #pragma unroll
                for (int r = 0; r < 4; ++r) {
                    mean[r] = sums[r] * (1.f / 256.f);
                    float var = (sqs[r] - sums[r] * sums[r] * (1.f / 256.f)) * (1.f / 255.f);
                    inv[r] = 1.f / (sqrtf(var) + 1e-6f);
                }
                if (L < 2) {
                    #pragma unroll
                    for (int ct = 0; ct < 16; ++ct) {
                        const float a_ = la[ct * 16 + lr], b_ = lb[ct * 16 + lr];
                        #pragma unroll
                        for (int r = 0; r < 4; ++r) {
                            float v  = acc[ct][r];
                            float sv = selu_f(v + (v - mean[r]) * inv[r] * a_ + b_);
                            const int row = 4 * g + r;
                            *(unsigned short*)(actw + ((row * 512 + (ct * 16 + lr) * 2) ^ (row << 5)))
                                = f2bf(sv);
                        }
                    }
                    asm volatile("s_waitcnt lgkmcnt(0)" ::: "memory");
                } else {
                    const float bo = b_out[n];
                    float ps[4] = {0,0,0,0};
                    #pragma unroll
                    for (int ct = 0; ct < 16; ++ct) {
                        const float a_ = la[ct * 16 + lr], b_ = lb[ct * 16 + lr];
                        const float w_ = P[ct * 16 + lr];   // wo
                        #pragma unroll
                        for (int r = 0; r < 4; ++r) {
                            float v  = acc[ct][r];
                            float sv = selu_f(v + (v - mean[r]) * inv[r] * a_ + b_);
                            ps[r] += sv * w_;
                        }
                    }
                    #pragma unroll
                    for (int r = 0; r < 4; ++r)
                        #pragma unroll
                        for (int m = 1; m <= 8; m <<= 1)
                            ps[r] += __shfl_xor(ps[r], m);
                    #pragma unroll
                    for (int r = 0; r < 4; ++r)
                        if (lr == r)
                            basesT[(size_t)(c * 16 + 4 * g + r) * NNET + n] = ps[r] + bo;
                }
            }
        } else {
            // producer body q: convert stage q+1 into tile[(q+1)&1]; issue q+2
            if (q + 1 < 24) {
                convert_store((q + 1) & 1);
                asm volatile("s_waitcnt lgkmcnt(0)" ::: "memory");
                if (q + 2 < 24) issue(q + 2);
            }
        }
        RAW_BAR();
    }
}

// score[b, jk] = sum_m x[b,m,jk>>1] * basesT[m][jk] * w[m]
__launch_bounds__(256)
__global__ void score_kernel(const float* __restrict__ x,
                             const float* __restrict__ t,
                             const float* __restrict__ basesT,
                             float* __restrict__ out)
{
    __shared__ float c_lds[M_GRID * 32];
    const int jt  = blockIdx.x;   // 0..4
    const int bt  = blockIdx.y;   // 0..255
    const int tid = threadIdx.x;

    for (int i = tid; i < M_GRID * 32; i += 256) {
        const int m  = i >> 5;
        const int jl = i & 31;
        const float tp = t[m == M_GRID - 1 ? M_GRID - 1 : m + 1];
        const float tm = t[m == 0 ? 0 : m - 1];
        c_lds[i] = basesT[(size_t)m * NNET + jt * 32 + jl] * 0.5f * (tp - tm);
    }
    __syncthreads();

    const int jj = tid & 31;
    const int bs = tid >> 5;
    const int jk = jt * 32 + jj;
    const int b  = bt * 8 + bs;
    const float* xp = x + (size_t)b * (M_GRID * J_FEAT) + (jk >> 1);
    float acc = 0.f;
    #pragma unroll 8
    for (int m = 0; m < M_GRID; ++m)
        acc += xp[(size_t)m * J_FEAT] * c_lds[m * 32 + jj];
    out[(size_t)b * NNET + jk] = acc;
}

extern "C" void kernel_launch(void* const* d_in, const int* in_sizes, int n_in,
                              void* d_out, int out_size, void* d_ws, size_t ws_size,
                              hipStream_t stream)
{
    const float* x     = (const float*)d_in[0];
    const float* t     = (const float*)d_in[1];
    const float* W_in  = (const float*)d_in[2];
    const float* b_in  = (const float*)d_in[3];
    const float* W_h   = (const float*)d_in[4];
    const float* b_h   = (const float*)d_in[5];
    const float* W_out = (const float*)d_in[6];
    const float* b_out = (const float*)d_in[7];
    const float* ln_a  = (const float*)d_in[8];
    const float* ln_b  = (const float*)d_in[9];
    float* basesT = (float*)d_ws;   // 128*160*4 = 80 KiB

    basis_kernel<<<dim3(NNET), dim3(1024), 112640, stream>>>(
        t, W_in, b_in, W_h, b_h, W_out, b_out, ln_a, ln_b, basesT);
    score_kernel<<<dim3(5, 256), dim3(256), 0, stream>>>(
        x, t, basesT, (float*)d_out);
}

// Round 17
// 123.550 us; speedup vs baseline: 2.2449x; 2.2449x over previous
//
#include <hip/hip_runtime.h>
#include <math.h>

#define M_GRID 128
#define J_FEAT 80
#define NNET   160   // NBASE*J_FEAT
#define HDIM   256

typedef __attribute__((ext_vector_type(8))) short v8s;   // 8 bf16
typedef __attribute__((ext_vector_type(4))) float f4;    // MFMA accum / float4

__device__ __forceinline__ unsigned short f2bf(float f) {
    unsigned u = __float_as_uint(f);
    u += 0x7fffu + ((u >> 16) & 1u);   // round-to-nearest-even
    return (unsigned short)(u >> 16);
}

__device__ __forceinline__ float selu_f(float x) {
    const float SC = 1.0507009873554805f;
    const float AL = 1.6732632423543772f;
    return x > 0.f ? SC * x : SC * AL * (__expf(x) - 1.f);
}

// ---------------------------------------------------------------------------
// Workspace layout (d_ws): actG bf16 @0 (10.5 MB), Y fp32 @12MB (21 MB),
// basesT @34MB (80 KB).  actG element (((n*8+rt)*8+s)*64 + l)*8 + i holds
// bf16 z[n][row=16rt+(l&15)][k=32s+8*(l>>4)+i]  == MFMA A-fragment order,
// so a GEMM wave loads its stage-s A-frag as ONE coalesced 1KB wave read.
// Rationale (r5-r16): per-CU streaming is wave-count-bound (~11 GB/s at 8
// waves, ~28 GB/s for fillBuffer at ~30 waves/CU).  One 160-block kernel
// idles 96 CUs and caps BW; so: many small blocks, one-shot LDS staging
// (no K-loop barriers, no pipeline), layers as separate kernels.
// ---------------------------------------------------------------------------

// input: z0 = t*wi + bi; z = selu(z0 + LN(z0)); write actG.  160 blocks.
__launch_bounds__(512, 1)
__global__ void input_kernel(const float* __restrict__ t,
                             const float* __restrict__ W_in,
                             const float* __restrict__ b_in,
                             const float* __restrict__ ln_a,
                             const float* __restrict__ ln_b,
                             unsigned short* __restrict__ actG)
{
    const int n  = blockIdx.x;
    const int tid = threadIdx.x, l = tid & 63, wv = tid >> 6;
    const int lr = l & 15, g = l >> 4;
    const float tval = t[wv * 16 + lr];
    const float* wi = W_in + (size_t)n * HDIM;
    const float* bi = b_in + (size_t)n * HDIM;
    const float* la = ln_a + (size_t)n * HDIM;   // layer 0
    const float* lb = ln_b + (size_t)n * HDIM;

    float z[8][8];
    float s_ = 0.f, q_ = 0.f;
    #pragma unroll
    for (int kt = 0; kt < 8; ++kt) {
        const int h0 = kt * 32 + g * 8;
        const f4 w0 = *(const f4*)(wi + h0), w1 = *(const f4*)(wi + h0 + 4);
        const f4 b0 = *(const f4*)(bi + h0), b1 = *(const f4*)(bi + h0 + 4);
        #pragma unroll
        for (int i = 0; i < 4; ++i) {
            z[kt][i]     = __builtin_fmaf(tval, w0[i], b0[i]);
            z[kt][i + 4] = __builtin_fmaf(tval, w1[i], b1[i]);
        }
        #pragma unroll
        for (int i = 0; i < 8; ++i) { s_ += z[kt][i]; q_ += z[kt][i] * z[kt][i]; }
    }
    s_ += __shfl_xor(s_, 16); q_ += __shfl_xor(q_, 16);
    s_ += __shfl_xor(s_, 32); q_ += __shfl_xor(q_, 32);
    const float mean = s_ * (1.f / 256.f);
    const float var  = (q_ - s_ * s_ * (1.f / 256.f)) * (1.f / 255.f); // unbiased
    const float inv  = 1.f / (sqrtf(var) + 1e-6f);                     // eps on std
    #pragma unroll
    for (int kt = 0; kt < 8; ++kt) {
        const int h0 = kt * 32 + g * 8;
        const f4 a0 = *(const f4*)(la + h0), a1 = *(const f4*)(la + h0 + 4);
        const f4 e0 = *(const f4*)(lb + h0), e1 = *(const f4*)(lb + h0 + 4);
        v8s a;
        #pragma unroll
        for (int i = 0; i < 4; ++i) {
            float v0 = z[kt][i], v1 = z[kt][i + 4];
            a[i]     = (short)f2bf(selu_f(v0 + (v0 - mean) * inv * a0[i] + e0[i]));
            a[i + 4] = (short)f2bf(selu_f(v1 + (v1 - mean) * inv * a1[i] + e1[i]));
        }
        *(v8s*)(actG + ((size_t)((n * 8 + wv) * 8 + kt) * 64 + l) * 8) = a;
    }
}

// gemm: Y[n][m][j0..j0+63] = actG[n] @ W[n][:, slice] + bias. grid (4, 160).
// One-shot LDS: whole W slice staged once, NO barriers in the K-loop.
__attribute__((amdgpu_flat_work_group_size(512, 512), amdgpu_waves_per_eu(4, 4)))
__global__ void gemm_kernel(const unsigned short* __restrict__ actG,
                            const float* __restrict__ Wl,   // + L*NNET*65536
                            const float* __restrict__ bhl,  // + L*NNET*256
                            float* __restrict__ Y)
{
    __shared__ unsigned short tile[16384];   // [64 j][256 k] bf16, XOR-swizzled
    const int jb = blockIdx.x, n = blockIdx.y, j0 = jb * 64;
    const int tid = threadIdx.x, l = tid & 63, wv = tid >> 6;
    const int lr = l & 15, g = l >> 4;
    const int jl = tid & 63, kc = tid >> 6;   // staging: column j0+jl, k-chunk kc

    // B: issue 32 loads (W[kc*32+i][j0+jl], coalesced 256B/wave per i)
    const float* src = Wl + (size_t)n * 65536 + (size_t)(kc * 32) * HDIM + j0 + jl;
    float wreg[32];
    #pragma unroll
    for (int i = 0; i < 32; ++i) wreg[i] = src[(size_t)i * HDIM];
    // A: issue 8 v8s (coalesced 1KB/wave, L3-hot) while B converts
    v8s av[8];
    const unsigned short* ab = actG + (size_t)((n * 8 + wv) * 8) * 512 + l * 8;
    #pragma unroll
    for (int s = 0; s < 8; ++s) av[s] = *(const v8s*)(ab + s * 512);
    // convert B -> swizzled LDS tile
    {
        const int cb = jl * 512 + kc * 64, cx = (jl & 15) << 5;
        #pragma unroll
        for (int o = 0; o < 4; ++o) {
            v8s pk;
            #pragma unroll
            for (int i = 0; i < 8; ++i) pk[i] = (short)f2bf(wreg[o * 8 + i]);
            *(v8s*)((unsigned char*)tile + ((cb + o * 16) ^ cx)) = pk;
        }
    }
    __syncthreads();

    f4 acc[4];
    const f4 zero = {0.f, 0.f, 0.f, 0.f};
    #pragma unroll
    for (int ct = 0; ct < 4; ++ct) acc[ct] = zero;
    #pragma unroll
    for (int s = 0; s < 8; ++s)
        #pragma unroll
        for (int ct = 0; ct < 4; ++ct) {
            const int byte = (((ct * 16 + lr) * 512 + s * 64 + g * 16) ^ (lr << 5));
            const v8s bf = *(const v8s*)((const unsigned char*)tile + byte);
            acc[ct] = __builtin_amdgcn_mfma_f32_16x16x32_bf16(av[s], bf, acc[ct], 0, 0, 0);
        }

    // epilogue: Y = acc + bias (pre-LN activation, fp32)
    #pragma unroll
    for (int ct = 0; ct < 4; ++ct) {
        const float bias = bhl[(size_t)n * HDIM + j0 + ct * 16 + lr];
        #pragma unroll
        for (int r = 0; r < 4; ++r) {
            const int m = wv * 16 + 4 * g + r;
            Y[(size_t)n * 32768 + (size_t)m * HDIM + j0 + ct * 16 + lr] = acc[ct][r] + bias;
        }
    }
}

// act: z = selu(y + LN(y)); write actG (A-frag order).  160 blocks.
__launch_bounds__(512, 1)
__global__ void act_kernel(const float* __restrict__ Y,
                           const float* __restrict__ la_,  // ln_a + (L+1)*NNET*256
                           const float* __restrict__ lb_,
                           unsigned short* __restrict__ actG)
{
    const int n  = blockIdx.x;
    const int tid = threadIdx.x, l = tid & 63, wv = tid >> 6;
    const int lr = l & 15, g = l >> 4;
    const float* yr = Y + (size_t)n * 32768 + (size_t)(wv * 16 + lr) * HDIM;
    const float* la = la_ + (size_t)n * HDIM;
    const float* lb = lb_ + (size_t)n * HDIM;

    float z[8][8];
    float s_ = 0.f, q_ = 0.f;
    #pragma unroll
    for (int kt = 0; kt < 8; ++kt) {
        const int h0 = kt * 32 + g * 8;
        const f4 y0 = *(const f4*)(yr + h0), y1 = *(const f4*)(yr + h0 + 4);
        #pragma unroll
        for (int i = 0; i < 4; ++i) { z[kt][i] = y0[i]; z[kt][i + 4] = y1[i]; }
        #pragma unroll
        for (int i = 0; i < 8; ++i) { s_ += z[kt][i]; q_ += z[kt][i] * z[kt][i]; }
    }
    s_ += __shfl_xor(s_, 16); q_ += __shfl_xor(q_, 16);
    s_ += __shfl_xor(s_, 32); q_ += __shfl_xor(q_, 32);
    const float mean = s_ * (1.f / 256.f);
    const float var  = (q_ - s_ * s_ * (1.f / 256.f)) * (1.f / 255.f);
    const float inv  = 1.f / (sqrtf(var) + 1e-6f);
    #pragma unroll
    for (int kt = 0; kt < 8; ++kt) {
        const int h0 = kt * 32 + g * 8;
        const f4 a0 = *(const f4*)(la + h0), a1 = *(const f4*)(la + h0 + 4);
        const f4 e0 = *(const f4*)(lb + h0), e1 = *(const f4*)(lb + h0 + 4);
        v8s a;
        #pragma unroll
        for (int i = 0; i < 4; ++i) {
            float v0 = z[kt][i], v1 = z[kt][i + 4];
            a[i]     = (short)f2bf(selu_f(v0 + (v0 - mean) * inv * a0[i] + e0[i]));
            a[i + 4] = (short)f2bf(selu_f(v1 + (v1 - mean) * inv * a1[i] + e1[i]));
        }
        *(v8s*)(actG + ((size_t)((n * 8 + wv) * 8 + kt) * 64 + l) * 8) = a;
    }
}

// final: z = selu(y + LN(y)); bases[m] = z . wo + bo; write basesT. 160 blocks.
__launch_bounds__(512, 1)
__global__ void final_kernel(const float* __restrict__ Y,
                             const float* __restrict__ la_,  // ln_a + 3*NNET*256
                             const float* __restrict__ lb_,
                             const float* __restrict__ W_out,
                             const float* __restrict__ b_out,
                             float* __restrict__ basesT)
{
    const int n  = blockIdx.x;
    const int tid = threadIdx.x, l = tid & 63, wv = tid >> 6;
    const int lr = l & 15, g = l >> 4;
    const float* yr = Y + (size_t)n * 32768 + (size_t)(wv * 16 + lr) * HDIM;
    const float* la = la_ + (size_t)n * HDIM;
    const float* lb = lb_ + (size_t)n * HDIM;
    const float* wo = W_out + (size_t)n * HDIM;

    float z[8][8];
    float s_ = 0.f, q_ = 0.f;
    #pragma unroll
    for (int kt = 0; kt < 8; ++kt) {
        const int h0 = kt * 32 + g * 8;
        const f4 y0 = *(const f4*)(yr + h0), y1 = *(const f4*)(yr + h0 + 4);
        #pragma unroll
        for (int i = 0; i < 4; ++i) { z[kt][i] = y0[i]; z[kt][i + 4] = y1[i]; }
        #pragma unroll
        for (int i = 0; i < 8; ++i) { s_ += z[kt][i]; q_ += z[kt][i] * z[kt][i]; }
    }
    s_ += __shfl_xor(s_, 16); q_ += __shfl_xor(q_, 16);
    s_ += __shfl_xor(s_, 32); q_ += __shfl_xor(q_, 32);
    const float mean = s_ * (1.f / 256.f);
    const float var  = (q_ - s_ * s_ * (1.f / 256.f)) * (1.f / 255.f);
    const float inv  = 1.f / (sqrtf(var) + 1e-6f);
    float ps = 0.f;
    #pragma unroll
    for (int kt = 0; kt < 8; ++kt) {
        const int h0 = kt * 32 + g * 8;
        const f4 a0 = *(const f4*)(la + h0), a1 = *(const f4*)(la + h0 + 4);
        const f4 e0 = *(const f4*)(lb + h0), e1 = *(const f4*)(lb + h0 + 4);
        const f4 w0 = *(const f4*)(wo + h0), w1 = *(const f4*)(wo + h0 + 4);
        #pragma unroll
        for (int i = 0; i < 4; ++i) {
            float v0 = z[kt][i], v1 = z[kt][i + 4];
            ps += selu_f(v0 + (v0 - mean) * inv * a0[i] + e0[i]) * w0[i];
            ps += selu_f(v1 + (v1 - mean) * inv * a1[i] + e1[i]) * w1[i];
        }
    }
    ps += __shfl_xor(ps, 16);
    ps += __shfl_xor(ps, 32);
    if (l < 16)
        basesT[(size_t)(wv * 16 + lr) * NNET + n] = ps + b_out[n];
}

// score[b, jk] = sum_m x[b,m,jk>>1] * basesT[m][jk] * w[m]
__launch_bounds__(256)
__global__ void score_kernel(const float* __restrict__ x,
                             const float* __restrict__ t,
                             const float* __restrict__ basesT,
                             float* __restrict__ out)
{
    __shared__ float c_lds[M_GRID * 32];
    const int jt  = blockIdx.x;   // 0..4
    const int bt  = blockIdx.y;   // 0..255
    const int tid = threadIdx.x;

    for (int i = tid; i < M_GRID * 32; i += 256) {
        const int m  = i >> 5;
        const int jl = i & 31;
        const float tp = t[m == M_GRID - 1 ? M_GRID - 1 : m + 1];
        const float tm = t[m == 0 ? 0 : m - 1];
        c_lds[i] = basesT[(size_t)m * NNET + jt * 32 + jl] * 0.5f * (tp - tm);
    }
    __syncthreads();

    const int jj = tid & 31;
    const int bs = tid >> 5;
    const int jk = jt * 32 + jj;
    const int b  = bt * 8 + bs;
    const float* xp = x + (size_t)b * (M_GRID * J_FEAT) + (jk >> 1);
    float acc = 0.f;
    #pragma unroll 8
    for (int m = 0; m < M_GRID; ++m)
        acc += xp[(size_t)m * J_FEAT] * c_lds[m * 32 + jj];
    out[(size_t)b * NNET + jk] = acc;
}

extern "C" void kernel_launch(void* const* d_in, const int* in_sizes, int n_in,
                              void* d_out, int out_size, void* d_ws, size_t ws_size,
                              hipStream_t stream)
{
    const float* x     = (const float*)d_in[0];
    const float* t     = (const float*)d_in[1];
    const float* W_in  = (const float*)d_in[2];
    const float* b_in  = (const float*)d_in[3];
    const float* W_h   = (const float*)d_in[4];
    const float* b_h   = (const float*)d_in[5];
    const float* W_out = (const float*)d_in[6];
    const float* b_out = (const float*)d_in[7];
    const float* ln_a  = (const float*)d_in[8];
    const float* ln_b  = (const float*)d_in[9];

    unsigned short* actG = (unsigned short*)d_ws;                    // 10.5 MB
    float* Yb   = (float*)((char*)d_ws + (12u << 20));               // 21 MB
    float* basesT = (float*)((char*)d_ws + (34u << 20));             // 80 KB

    input_kernel<<<dim3(NNET), dim3(512), 0, stream>>>(
        t, W_in, b_in, ln_a, ln_b, actG);
    for (int L = 0; L < 3; ++L) {
        gemm_kernel<<<dim3(4, NNET), dim3(512), 0, stream>>>(
            actG, W_h + (size_t)L * NNET * 65536, b_h + (size_t)L * NNET * 256, Yb);
        if (L < 2)
            act_kernel<<<dim3(NNET), dim3(512), 0, stream>>>(
                Yb, ln_a + (size_t)(L + 1) * NNET * 256,
                ln_b + (size_t)(L + 1) * NNET * 256, actG);
    }
    final_kernel<<<dim3(NNET), dim3(512), 0, stream>>>(
        Yb, ln_a + (size_t)3 * NNET * 256, ln_b + (size_t)3 * NNET * 256,
        W_out, b_out, basesT);
    score_kernel<<<dim3(5, 256), dim3(256), 0, stream>>>(
        x, t, basesT, (float*)d_out);
}

// Round 18
// 123.096 us; speedup vs baseline: 2.2532x; 1.0037x over previous
//
#include <hip/hip_runtime.h>
#include <math.h>

#define M_GRID 128
#define J_FEAT 80
#define NNET   160   // NBASE*J_FEAT
#define HDIM   256

typedef __attribute__((ext_vector_type(8))) short v8s;   // 8 bf16
typedef __attribute__((ext_vector_type(4))) float f4;    // MFMA accum / float4

__device__ __forceinline__ unsigned short f2bf(float f) {
    unsigned u = __float_as_uint(f);
    u += 0x7fffu + ((u >> 16) & 1u);   // round-to-nearest-even
    return (unsigned short)(u >> 16);
}

__device__ __forceinline__ float selu_f(float x) {
    const float SC = 1.0507009873554805f;
    const float AL = 1.6732632423543772f;
    return x > 0.f ? SC * x : SC * AL * (__expf(x) - 1.f);
}

#define FENCE_BAR() do { asm volatile("s_waitcnt lgkmcnt(0)" ::: "memory"); \
                         __builtin_amdgcn_sched_barrier(0);                 \
                         __builtin_amdgcn_s_barrier(); } while (0)

// One workgroup per network n. 256 threads = 4 waves; wave w owns rows
// 32w..32w+31 as two 16-row tiles; acc[2][16] = 128 AGPRs; one B-fragment
// feeds both tiles.  Register regime: r7 proved 256-thr + waves_per_eu(1,1)
// grants 256 arch VGPRs (the 512-thr configs were allocator-capped at 128
// and spilled in r9/r11/r14/r15).  Staging: ordinary VMEM (the DMA engine
// is ~8-requests-deep -> 13 GB/s/CU cold, r5-r17) into TWO NAMED 32-reg
// sets (rrA/rrB, static indexing only), depth-2 pipeline = 64 KB/CU in
// flight, converted to the r15-proven XOR-swizzled double-buffered bf16
// tile; ONE barrier per stage; every wait compiler-counted on exact regs.
// Activations live in LDS (r10): epilogues write act directly, no afrag.
// Arch demand ~110 of 256 -> no spill possible.
// LDS 110 KB: tiles 2x16K @0, act @32K (4 waves x 16K), params @96K (14 KB).
__attribute__((amdgpu_flat_work_group_size(256, 256), amdgpu_waves_per_eu(1, 1)))
__global__ void basis_kernel(const float* __restrict__ t,
                             const float* __restrict__ W_in,
                             const float* __restrict__ b_in,
                             const float* __restrict__ W_h,
                             const float* __restrict__ b_h,
                             const float* __restrict__ W_out,
                             const float* __restrict__ b_out,
                             const float* __restrict__ ln_a,
                             const float* __restrict__ ln_b,
                             float* __restrict__ basesT)   // [M][NNET]
{
    extern __shared__ __align__(16) unsigned char lds[];   // 112640 B
    const int n    = blockIdx.x;
    const int tid  = threadIdx.x;
    const int l    = tid & 63;
    const int wv   = tid >> 6;      // wave 0..3
    const int lr   = l & 15;
    const int g    = l >> 4;        // k-group
    const int jcol = tid;           // staging column 0..255

    unsigned char* const actw = lds + 32768 + (size_t)wv * 16384; // 2 tiles x 8K
    float* const P = (float*)(lds + 98304);
    // P groups (256 floats): 0=wo, 1-3=ln_a L1..3, 4-6=ln_b L1..3,
    // 7-9=b_h L0..2, 10=wi, 11=bi, 12=ln_a L0, 13=ln_b L0.

    // -------- staging helpers (static reg sets; r15 tile layout/swizzle) -----
    float rrA[32], rrB[32];
    auto issueA = [&](int q) {
        const float* Wq = W_h + ((size_t)((q >> 3) * NNET + n) << 16)
                        + (size_t)((q & 7) * 32) * HDIM + jcol;
        #pragma unroll
        for (int i = 0; i < 32; ++i) rrA[i] = Wq[(size_t)i * HDIM];
    };
    auto issueB = [&](int q) {
        const float* Wq = W_h + ((size_t)((q >> 3) * NNET + n) << 16)
                        + (size_t)((q & 7) * 32) * HDIM + jcol;
        #pragma unroll
        for (int i = 0; i < 32; ++i) rrB[i] = Wq[(size_t)i * HDIM];
    };
    auto convA = [&](int bufp) {   // tile layout [2 kh][256 j][16 k] bf16
        #pragma unroll
        for (int o = 0; o < 4; ++o) {
            v8s pk;
            #pragma unroll
            for (int i = 0; i < 8; ++i) pk[i] = (short)f2bf(rrA[o * 8 + i]);
            int byte = (bufp << 14) + ((o >> 1) << 13) + jcol * 32 + ((o & 1) << 4);
            byte ^= ((jcol >> 2) & 7) << 4;
            *(v8s*)(lds + byte) = pk;
        }
    };
    auto convB = [&](int bufp) {
        #pragma unroll
        for (int o = 0; o < 4; ++o) {
            v8s pk;
            #pragma unroll
            for (int i = 0; i < 8; ++i) pk[i] = (short)f2bf(rrB[o * 8 + i]);
            int byte = (bufp << 14) + ((o >> 1) << 13) + jcol * 32 + ((o & 1) << 4);
            byte ^= ((jcol >> 2) & 7) << 4;
            *(v8s*)(lds + byte) = pk;
        }
    };

    issueA(0);
    issueB(1);

    // -------- params -> LDS (each thread: one element of all 14 groups) ------
    {
        const size_t nb = (size_t)n * HDIM;
        #pragma unroll
        for (int grp = 0; grp < 14; ++grp) {
            float v;
            if (grp == 0)       v = W_out[nb + tid];
            else if (grp < 4)   v = ln_a[((size_t)grp * NNET + n) * HDIM + tid];
            else if (grp < 7)   v = ln_b[((size_t)(grp - 3) * NNET + n) * HDIM + tid];
            else if (grp < 10)  v = b_h[((size_t)(grp - 7) * NNET + n) * HDIM + tid];
            else if (grp == 10) v = W_in[nb + tid];
            else if (grp == 11) v = b_in[nb + tid];
            else if (grp == 12) v = ln_a[nb + tid];
            else                v = ln_b[nb + tid];
            P[grp * 256 + tid] = v;
        }
    }
    FENCE_BAR();   // params visible; rrA/rrB loads stay in flight

    // -------- input layer (two 16-row tiles per wave; two-pass, to act) ------
    {
        const float* wi = P + 2560; const float* bi = P + 2816;
        const float* la = P + 3072; const float* lb = P + 3328;
        #pragma unroll
        for (int tt = 0; tt < 2; ++tt) {
            const float tval = t[wv * 32 + tt * 16 + lr];
            float s_ = 0.f, q_ = 0.f;
            #pragma unroll
            for (int kt = 0; kt < 8; ++kt) {
                const int h0 = kt * 32 + g * 8;
                const f4 w0 = *(const f4*)(wi + h0), w1 = *(const f4*)(wi + h0 + 4);
                const f4 b0 = *(const f4*)(bi + h0), b1 = *(const f4*)(bi + h0 + 4);
                #pragma unroll
                for (int i = 0; i < 4; ++i) {
                    float v0 = __builtin_fmaf(tval, w0[i], b0[i]);
                    float v1 = __builtin_fmaf(tval, w1[i], b1[i]);
                    s_ += v0 + v1; q_ += v0 * v0 + v1 * v1;
                }
            }
            s_ += __shfl_xor(s_, 16); q_ += __shfl_xor(q_, 16);
            s_ += __shfl_xor(s_, 32); q_ += __shfl_xor(q_, 32);
            const float mean = s_ * (1.f / 256.f);
            const float var  = (q_ - s_ * s_ * (1.f / 256.f)) * (1.f / 255.f); // unbiased
            const float inv  = 1.f / (sqrtf(var) + 1e-6f);                     // eps on std
            asm volatile("" ::: "memory");   // forbid CSE of pass-1 reads
            #pragma unroll
            for (int kt = 0; kt < 8; ++kt) {
                const int h0 = kt * 32 + g * 8;
                const f4 w0 = *(const f4*)(wi + h0), w1 = *(const f4*)(wi + h0 + 4);
                const f4 b0 = *(const f4*)(bi + h0), b1 = *(const f4*)(bi + h0 + 4);
                const f4 a0 = *(const f4*)(la + h0), a1 = *(const f4*)(la + h0 + 4);
                const f4 e0 = *(const f4*)(lb + h0), e1 = *(const f4*)(lb + h0 + 4);
                v8s a;
                #pragma unroll
                for (int i = 0; i < 4; ++i) {
                    float v0 = __builtin_fmaf(tval, w0[i], b0[i]);
                    float v1 = __builtin_fmaf(tval, w1[i], b1[i]);
                    a[i]     = (short)f2bf(selu_f(v0 + (v0 - mean) * inv * a0[i] + e0[i]));
                    a[i + 4] = (short)f2bf(selu_f(v1 + (v1 - mean) * inv * a1[i] + e1[i]));
                }
                *(v8s*)(actw + tt * 8192 + ((lr * 512 + h0 * 2) ^ (lr << 5))) = a;
            }
            asm volatile("" ::: "memory");
        }
        asm volatile("s_waitcnt lgkmcnt(0)" ::: "memory");  // act wave-private
    }

    // -------- prologue: tile0 <- rrA(stage0); refill rrA with stage 2 --------
    convA(0);          // compiler waits exactly on rrA's loads
    issueA(2);
    FENCE_BAR();       // tile0 visible

    f4 acc[2][16];

    auto mfma_body = [&](int q, int tb) {
        const int sq = q & 7;
        const v8s afA = *(const v8s*)(actw + ((lr * 512 + (sq * 32 + g * 8) * 2) ^ (lr << 5)));
        const v8s afB = *(const v8s*)(actw + 8192 + ((lr * 512 + (sq * 32 + g * 8) * 2) ^ (lr << 5)));
        #pragma unroll
        for (int ct = 0; ct < 16; ++ct) {
            const int jb = ct * 16 + lr;
            int byte = (tb << 14) + ((g >> 1) << 13) + jb * 32 + ((g & 1) << 4);
            byte ^= ((jb >> 2) & 7) << 4;
            const v8s bf = *(const v8s*)(lds + byte);
            acc[0][ct] = __builtin_amdgcn_mfma_f32_16x16x32_bf16(afA, bf, acc[0][ct], 0, 0, 0);
            acc[1][ct] = __builtin_amdgcn_mfma_f32_16x16x32_bf16(afB, bf, acc[1][ct], 0, 0, 0);
        }
    };
    auto epilogue = [&](int L) {
        const float* bh = P + (7 + L) * 256;
        const float* la = P + (1 + L) * 256;
        const float* lb = P + (4 + L) * 256;
        #pragma unroll
        for (int tt = 0; tt < 2; ++tt) {
            float sums[4] = {0,0,0,0}, sqs[4] = {0,0,0,0};
            #pragma unroll
            for (int ct = 0; ct < 16; ++ct) {
                const float bias = bh[ct * 16 + lr];
                #pragma unroll
                for (int r = 0; r < 4; ++r) {
                    float v = acc[tt][ct][r] + bias;
                    acc[tt][ct][r] = v;
                    sums[r] += v; sqs[r] += v * v;
                }
            }
            #pragma unroll
            for (int r = 0; r < 4; ++r)
                #pragma unroll
                for (int m = 1; m <= 8; m <<= 1) {
                    sums[r] += __shfl_xor(sums[r], m);
                    sqs[r]  += __shfl_xor(sqs[r],  m);
                }
            float mean[4], inv[4];
            #pragma unroll
            for (int r = 0; r < 4; ++r) {
                mean[r] = sums[r] * (1.f / 256.f);
                float var = (sqs[r] - sums[r] * sums[r] * (1.f / 256.f)) * (1.f / 255.f);
                inv[r] = 1.f / (sqrtf(var) + 1e-6f);
            }
            if (L < 2) {
                #pragma unroll
                for (int ct = 0; ct < 16; ++ct) {
                    const float a_ = la[ct * 16 + lr], b_ = lb[ct * 16 + lr];
                    #pragma unroll
                    for (int r = 0; r < 4; ++r) {
                        float v  = acc[tt][ct][r];
                        float sv = selu_f(v + (v - mean[r]) * inv[r] * a_ + b_);
                        const int row = 4 * g + r;
                        *(unsigned short*)(actw + tt * 8192
                            + ((row * 512 + (ct * 16 + lr) * 2) ^ (row << 5))) = f2bf(sv);
                    }
                }
            } else {
                const float bo = b_out[n];
                float ps[4] = {0,0,0,0};
                #pragma unroll
                for (int ct = 0; ct < 16; ++ct) {
                    const float a_ = la[ct * 16 + lr], b_ = lb[ct * 16 + lr];
                    const float w_ = P[ct * 16 + lr];   // wo
                    #pragma unroll
                    for (int r = 0; r < 4; ++r) {
                        float v  = acc[tt][ct][r];
                        float sv = selu_f(v + (v - mean[r]) * inv[r] * a_ + b_);
                        ps[r] += sv * w_;
                    }
                }
                #pragma unroll
                for (int r = 0; r < 4; ++r)
                    #pragma unroll
                    for (int m = 1; m <= 8; m <<= 1)
                        ps[r] += __shfl_xor(ps[r], m);
                #pragma unroll
                for (int r = 0; r < 4; ++r)
                    if (lr == r)
                        basesT[(size_t)(wv * 32 + tt * 16 + 4 * g + r) * NNET + n] = ps[r] + bo;
            }
        }
        asm volatile("s_waitcnt lgkmcnt(0)" ::: "memory");  // act writes done
    };

    // -------- K pipeline: 24 stages, processed in parity pairs --------
    #pragma unroll 1
    for (int p = 0; p < 12; ++p) {
        // even sub-body: MFMA stage 2p (tile0); conv stage 2p+1 -> tile1
        {
            const int q = 2 * p;
            if ((q & 7) == 0) {
                const f4 zero = {0.f, 0.f, 0.f, 0.f};
                #pragma unroll
                for (int tt = 0; tt < 2; ++tt)
                    #pragma unroll
                    for (int ct = 0; ct < 16; ++ct) acc[tt][ct] = zero;
            }
            convB(1);                          // stage 2p+1 (issued 2 sub-bodies ago)
            if (2 * p + 3 < 24) issueB(2 * p + 3);
            mfma_body(q, 0);
            FENCE_BAR();
        }
        // odd sub-body: MFMA stage 2p+1 (tile1); conv stage 2p+2 -> tile0
        {
            const int q = 2 * p + 1;
            if (2 * p + 2 < 24) {
                convA(0);                      // stage 2p+2
                if (2 * p + 4 < 24) issueA(2 * p + 4);
            }
            mfma_body(q, 1);
            if ((q & 7) == 7) epilogue(q >> 3);
            if (p < 11) FENCE_BAR();
        }
    }
}

// score[b, jk] = sum_m x[b,m,jk>>1] * basesT[m][jk] * w[m]
__launch_bounds__(256)
__global__ void score_kernel(const float* __restrict__ x,
                             const float* __restrict__ t,
                             const float* __restrict__ basesT,
                             float* __restrict__ out)
{
    __shared__ float c_lds[M_GRID * 32];
    const int jt  = blockIdx.x;   // 0..4
    const int bt  = blockIdx.y;   // 0..255
    const int tid = threadIdx.x;

    for (int i = tid; i < M_GRID * 32; i += 256) {
        const int m  = i >> 5;
        const int jl = i & 31;
        const float tp = t[m == M_GRID - 1 ? M_GRID - 1 : m + 1];
        const float tm = t[m == 0 ? 0 : m - 1];
        c_lds[i] = basesT[(size_t)m * NNET + jt * 32 + jl] * 0.5f * (tp - tm);
    }
    __syncthreads();

    const int jj = tid & 31;
    const int bs = tid >> 5;
    const int jk = jt * 32 + jj;
    const int b  = bt * 8 + bs;
    const float* xp = x + (size_t)b * (M_GRID * J_FEAT) + (jk >> 1);
    float acc = 0.f;
    #pragma unroll 8
    for (int m = 0; m < M_GRID; ++m)
        acc += xp[(size_t)m * J_FEAT] * c_lds[m * 32 + jj];
    out[(size_t)b * NNET + jk] = acc;
}

extern "C" void kernel_launch(void* const* d_in, const int* in_sizes, int n_in,
                              void* d_out, int out_size, void* d_ws, size_t ws_size,
                              hipStream_t stream)
{
    const float* x     = (const float*)d_in[0];
    const float* t     = (const float*)d_in[1];
    const float* W_in  = (const float*)d_in[2];
    const float* b_in  = (const float*)d_in[3];
    const float* W_h   = (const float*)d_in[4];
    const float* b_h   = (const float*)d_in[5];
    const float* W_out = (const float*)d_in[6];
    const float* b_out = (const float*)d_in[7];
    const float* ln_a  = (const float*)d_in[8];
    const float* ln_b  = (const float*)d_in[9];
    float* basesT = (float*)d_ws;   // 128*160*4 = 80 KiB

    basis_kernel<<<dim3(NNET), dim3(256), 112640, stream>>>(
        t, W_in, b_in, W_h, b_h, W_out, b_out, ln_a, ln_b, basesT);
    score_kernel<<<dim3(5, 256), dim3(256), 0, stream>>>(
        x, t, basesT, (float*)d_out);
}